// Round 14
// baseline (227.968 us; speedup 1.0000x reference)
//
#include <hip/hip_runtime.h>
#include <hip/hip_bf16.h>
#include <hip/hip_cooperative_groups.h>

namespace cg = cooperative_groups;

#define BB 4
#define LL 512
#define NTYPES 20
#define HH 6
#define DKK 10
#define DMM 60
#define PROW 516        // residue-major padded row: 3 regions x 172
#define NWROW 516
#define NBLK 512
#define SCALE 0.31622776601683794f

// ---------------- helpers ----------------
__device__ __forceinline__ float softplus_fast(float x) {
    return fmaxf(x, 0.0f) + __logf(1.0f + __expf(-fabsf(x)));
}

// one attention row: no-max softmax, residue-major p store, PV -> vmupre
__device__ __forceinline__ void attn_row(int bh, int i, int lane,
        const float* __restrict__ q, const float* __restrict__ kT_,
        const float* __restrict__ vT_,
        __hip_bfloat16* __restrict__ pbuf, float* __restrict__ vmupre)
{
    float qr[DKK];
    #pragma unroll
    for (int d = 0; d < DKK; ++d) qr[d] = q[((size_t)bh * LL + i) * DKK + d];
    int nchunk = (i >> 6) + 1;
    float e[8];
    float S = 0.0f;
    #pragma unroll
    for (int c = 0; c < 8; ++c) {
        e[c] = 0.0f;
        if (c < nchunk) {
            int j = c * 64 + lane;
            float dot = 0.0f;
            #pragma unroll
            for (int d = 0; d < DKK; ++d) dot += qr[d] * kT_[d * LL + j];
            if (j <= i) e[c] = __expf(dot * SCALE);
            S += e[c];
        }
    }
    #pragma unroll
    for (int off = 32; off >= 1; off >>= 1) S += __shfl_xor(S, off, 64);
    float inv = 1.0f / S;
    __hip_bfloat16* prow = pbuf + (size_t)(bh * LL + i) * PROW;
    #pragma unroll
    for (int c = 0; c < 8; ++c) {
        if (c < nchunk) {
            int j = c * 64 + lane;
            int slot = (j % 3) * 172 + j / 3;
            if (j <= i) prow[slot] = __float2bfloat16(e[c] * inv);
        }
    }
    float acc[DKK];
    #pragma unroll
    for (int d = 0; d < DKK; ++d) acc[d] = 0.0f;
    #pragma unroll
    for (int c = 0; c < 8; ++c) {
        if (c < nchunk) {
            int j = c * 64 + lane;
            #pragma unroll
            for (int d = 0; d < DKK; ++d) acc[d] += e[c] * vT_[d * LL + j];
        }
    }
    #pragma unroll
    for (int d = 0; d < DKK; ++d) {
        float a = acc[d];
        #pragma unroll
        for (int off = 32; off >= 1; off >>= 1) a += __shfl_xor(a, off, 64);
        acc[d] = a;
    }
    if (lane == 0) {
        #pragma unroll
        for (int d = 0; d < DKK; ++d)
            vmupre[((size_t)bh * LL + i) * DKK + d] = acc[d] * inv;
    }
}

// ---------------- the whole pipeline, one cooperative launch ----------------
__global__ __launch_bounds__(256, 2) void ishp_all(
        const float* __restrict__ ev, const float* __restrict__ embed_w,
        const float* __restrict__ qw, const float* __restrict__ qb,
        const float* __restrict__ kw, const float* __restrict__ kb,
        const float* __restrict__ vw, const float* __restrict__ vb,
        const float* __restrict__ aw, const float* __restrict__ gw,
        const float* __restrict__ ab, const float* __restrict__ gb,
        const float* __restrict__ muw, const float* __restrict__ mub,
        float* __restrict__ q, float* __restrict__ kT, float* __restrict__ vT,
        float* __restrict__ vmupre, float* __restrict__ Wbuf,
        __hip_bfloat16* __restrict__ pbuf,
        float* __restrict__ out_mu, float* __restrict__ outA, float* __restrict__ outG)
{
    cg::grid_group grid = cg::this_grid();
    __shared__ float smem[5120];
    __shared__ float sv[DMM];
    int blk = blockIdx.x;
    int tid = threadIdx.x;
    int lane = tid & 63;

    // ---- Phase 1: qkv + W precompute, 4 positions per block ----
    for (int s = 0; s < 4; ++s) {
        int pos = (blk << 2) + s;        // b*L + l
        int b = pos >> 9, l = pos & 511;
        if (tid == 0) {
            float t1 = ev[(b * (LL + 1) + l) * 2 + 0];
            float t0 = (l > 0) ? ev[(b * (LL + 1) + l - 1) * 2 + 0] : 0.0f;
            smem[0] = t1 - t0;
        } else if (tid < DMM) {
            int type = (int)ev[(b * (LL + 1) + l) * 2 + 1];
            smem[tid] = embed_w[(tid - 1) * NTYPES + type];
        }
        __syncthreads();
        if (tid < 180) {
            int which = tid / DMM;
            int m = tid - which * DMM;
            const float* w  = which == 0 ? qw : which == 1 ? kw : vw;
            const float* bs = which == 0 ? qb : which == 1 ? kb : vb;
            float sacc = bs[m];
            #pragma unroll
            for (int c = 0; c < DMM; ++c) sacc += smem[c] * w[m * DMM + c];
            int h = m / DKK, d = m - h * DKK;
            if (which == 0)      q [((b * HH + h) * LL + l) * DKK + d] = sacc;
            else if (which == 1) kT[((b * HH + h) * DKK + d) * LL + l] = sacc;
            else { vT[((b * HH + h) * DKK + d) * LL + l] = sacc; sv[m] = sacc; }
        }
        __syncthreads();
        if (tid < 180) {
            int kk = tid % 10;
            int u = tid / 10;            // 0..17
            int h  = u % 3;
            int cc = (u / 3) % 3;
            int mat = u / 9;             // 0 = alpha, 1 = gamma
            const float* w = mat ? gw : aw;
            float sacc = 0.0f;
            #pragma unroll
            for (int d = 0; d < DKK; ++d) sacc += w[kk * 30 + cc * 10 + d] * sv[(h + 3 * mat) * DKK + d];
            int slot = (l % 3) * 172 + l / 3;
            Wbuf[((size_t)((((mat * 3 + cc) * 4 + b) * 3 + h) * 10 + kk)) * NWROW + slot] = sacc;
        }
        __syncthreads();
    }
    grid.sync();

    // ---- Phase 2: attention, cost-balanced row pairs (p, 511-p), 3 tasks/wave ----
    int gwave = (blk << 2) + (tid >> 6);   // 0..2047
    for (int task = gwave; task < 6144; task += 2048) {
        int bh = task >> 8;                // 0..23
        int p = task & 255;
        const float* kT_ = kT + (size_t)bh * DKK * LL;
        const float* vT_ = vT + (size_t)bh * DKK * LL;
        attn_row(bh, p, lane, q, kT_, vT_, pbuf, vmupre);
        attn_row(bh, 511 - p, lane, q, kT_, vT_, pbuf, vmupre);
    }
    grid.sync();

    // ---- Phase 3: v_alpha / v_gamma (+ v_mu on tiles 0..7), 8 tiles per block ----
    for (int s = 0; s < 8; ++s) {
        int tile = (s << 9) + blk;         // 0..4095 (strided: tiles 0..7 on blocks 0..7)
        int pos = (tile << 8) + tid;
        int b  = pos >> 18;
        int i2 = (pos >> 9) & 511;
        int j2 = pos & 511;

        float ra[DKK], rg[DKK];
        if (j2 > i2) {
            #pragma unroll
            for (int kk = 0; kk < DKK; ++kk) { ra[kk] = 0.0f; rg[kk] = 0.0f; }
        } else {
            #pragma unroll
            for (int kk = 0; kk < DKK; ++kk) { ra[kk] = ab[kk]; rg[kk] = gb[kk]; }
            #pragma unroll
            for (int cc = 0; cc < 3; ++cc) {
                int u = 3 * j2 + cc;
                int sel = u >> 9;
                int j = u & 511;
                int hi = 3 * i2 + sel;
                int h = hi >> 9;
                int i = hi & 511;
                int jq = j / 3;
                int r = j - 3 * jq;
                int slot = r * 172 + jq;
                float pa = 0.0f, pg = 0.0f;
                if (j <= i) {
                    pa = __bfloat162float(pbuf[(size_t)((b * HH + h) * LL + i) * PROW + slot]);
                    pg = __bfloat162float(pbuf[(size_t)((b * HH + h + 3) * LL + i) * PROW + slot]);
                }
                const float* Wa = Wbuf + ((size_t)(((0 + cc) * 4 + b) * 3 + h) * 10) * NWROW + slot;
                const float* Wg = Wbuf + ((size_t)(((3 + cc) * 4 + b) * 3 + h) * 10) * NWROW + slot;
                #pragma unroll
                for (int kk = 0; kk < DKK; ++kk) {
                    ra[kk] += pa * Wa[kk * NWROW];
                    rg[kk] += pg * Wg[kk * NWROW];
                }
            }
            #pragma unroll
            for (int kk = 0; kk < DKK; ++kk) {
                ra[kk] = softplus_fast(ra[kk]);
                rg[kk] = softplus_fast(10.0f * rg[kk]) * 0.1f;
            }
        }
        __syncthreads();   // prior tile's LDS reads complete before overwrite
        #pragma unroll
        for (int kk = 0; kk < DKK; ++kk) {
            smem[tid * 10 + kk] = ra[kk];
            smem[2560 + tid * 10 + kk] = rg[kk];
        }
        __syncthreads();
        size_t base = (size_t)tile * 2560;
        #pragma unroll
        for (int it = 0; it < 3; ++it) {
            int idx = it * 1024 + tid * 4;
            if (idx < 2560) {
                *reinterpret_cast<float4*>(outA + base + idx) = *reinterpret_cast<const float4*>(&smem[idx]);
                *reinterpret_cast<float4*>(outG + base + idx) = *reinterpret_cast<const float4*>(&smem[2560 + idx]);
            }
        }
        if (tile < 8) {
            int mpos = (tile << 8) + tid;    // b*L + l
            int mb = mpos >> 9, ml = mpos & 511;
            float y[DKK];
            #pragma unroll
            for (int kk = 0; kk < DKK; ++kk) y[kk] = mub[kk];
            for (int c = 0; c < DMM; ++c) {
                int h = c / DKK, d = c - h * DKK;
                float xc = vmupre[((mb * HH + h) * LL + ml) * DKK + d];
                #pragma unroll
                for (int kk = 0; kk < DKK; ++kk) y[kk] += xc * muw[kk * DMM + c];
            }
            #pragma unroll
            for (int kk = 0; kk < DKK; ++kk)
                out_mu[(size_t)mpos * DKK + kk] = 1.0f / (1.0f + __expf(-y[kk]));
        }
    }
}

// ---------------- launch ----------------
extern "C" void kernel_launch(void* const* d_in, const int* in_sizes, int n_in,
                              void* d_out, int out_size, void* d_ws, size_t ws_size,
                              hipStream_t stream) {
    const float *ev = 0, *emb = 0, *muw = 0;
    const float *w3[3] = {0, 0, 0}, *b3[3] = {0, 0, 0};
    const float *w300[2] = {0, 0};
    const float *b10[3] = {0, 0, 0};
    int n3 = 0, nb3 = 0, n300 = 0, n10 = 0;
    for (int i = 0; i < n_in; ++i) {
        int s = in_sizes[i];
        if      (s == 4104) ev  = (const float*)d_in[i];
        else if (s == 1180) emb = (const float*)d_in[i];
        else if (s == 600)  muw = (const float*)d_in[i];
        else if (s == 3600) { if (n3  < 3) w3[n3++]   = (const float*)d_in[i]; }
        else if (s == 60)   { if (nb3 < 3) b3[nb3++]  = (const float*)d_in[i]; }
        else if (s == 300)  { if (n300< 2) w300[n300++]=(const float*)d_in[i]; }
        else if (s == 10)   { if (n10 < 3) b10[n10++] = (const float*)d_in[i]; }
    }

    float* ws = (float*)d_ws;
    float* q = ws;
    float* kT = q + 122880;
    float* vT = kT + 122880;
    float* vmupre = vT + 122880;
    float* Wbuf = vmupre + 122880;
    __hip_bfloat16* pbuf = (__hip_bfloat16*)(Wbuf + 371520);

    float* out = (float*)d_out;
    float* out_mu = out;
    float* out_a  = out + 20480;
    float* out_g  = out + 20480 + 10485760;

    void* kargs[] = {
        (void*)&ev, (void*)&emb,
        (void*)&w3[0], (void*)&b3[0], (void*)&w3[1], (void*)&b3[1],
        (void*)&w3[2], (void*)&b3[2],
        (void*)&w300[0], (void*)&w300[1],
        (void*)&b10[0], (void*)&b10[1],
        (void*)&muw, (void*)&b10[2],
        (void*)&q, (void*)&kT, (void*)&vT, (void*)&vmupre, (void*)&Wbuf,
        (void*)&pbuf,
        (void*)&out_mu, (void*)&out_a, (void*)&out_g
    };
    hipLaunchCooperativeKernel((const void*)ishp_all, dim3(NBLK), dim3(256),
                               kargs, 0, stream);
}